// Round 12
// baseline (378.204 us; speedup 1.0000x reference)
//
#include <hip/hip_runtime.h>
#include <hip/hip_cooperative_groups.h>
#include <hip/hip_bf16.h>

namespace cg = cooperative_groups;

typedef __attribute__((ext_vector_type(8))) short bf16x8;
typedef __attribute__((ext_vector_type(4))) float f32x4;

__device__ __forceinline__ unsigned short f2b(float f) {
    union { float f; unsigned int u; } v; v.f = f;
    unsigned int u = v.u;
    unsigned int r = (u + 0x7FFFu + ((u >> 16) & 1u)) >> 16;  // RNE
    return (unsigned short)r;
}
__device__ __forceinline__ float b2f(unsigned short h) {
    union { unsigned int u; float f; } v; v.u = ((unsigned int)h) << 16;
    return v.f;
}
__device__ __forceinline__ unsigned pk2(float a, float b) {
    union { __hip_bfloat162 h; unsigned u; } c;
    c.h = __float22bfloat162_rn(make_float2(a, b));
    return c.u;
}

struct SMemGemm { unsigned short As[64 * 72]; unsigned short Bs[64 * 72]; };
struct SMemAttn { float Om[4][32][33]; float Ls[4][32]; };
struct SMemPrep { float Ts[32][65]; };
union SMemU { SMemGemm g; SMemAttn a; SMemPrep p; };

// ---------------- phase bodies (round-10 proven versions) ----------------

__device__ __forceinline__ void prep_body(int b, SMemU& sm,
    const float* __restrict__ WQ, const float* __restrict__ WK,
    const float* __restrict__ WV,
    const float* __restrict__ Qb, const float* __restrict__ Kb,
    const float* __restrict__ Vb,
    unsigned short* __restrict__ WQt, unsigned short* __restrict__ WKt,
    unsigned short* __restrict__ WVt,
    unsigned short* __restrict__ Bq, unsigned short* __restrict__ Bk,
    unsigned short* __restrict__ Bv) {
    int t = threadIdx.x;
    if (b < 288) {
        const float* W; unsigned short* Wt; int h, d0, D; float sc = 1.0f;
        if (b < 128)      { W = WQ; Wt = WQt; h = b >> 4;   d0 = (b & 15) * 64; D = 1024; sc = 0.0625f; }
        else if (b < 256) { int bb = b - 128; W = WK; Wt = WKt; h = bb >> 4; d0 = (bb & 15) * 64; D = 1024; }
        else              { int bb = b - 256; W = WV; Wt = WVt; h = bb >> 2; d0 = (bb & 3) * 64;  D = 256; }
        int dr = t >> 2, k0 = (t & 3) * 8;
        const float* src = W + (h * D + d0 + dr) * 32 + k0;
        float4 u0 = *(const float4*)src;
        float4 u1 = *(const float4*)(src + 4);
        sm.p.Ts[k0 + 0][dr] = u0.x; sm.p.Ts[k0 + 1][dr] = u0.y;
        sm.p.Ts[k0 + 2][dr] = u0.z; sm.p.Ts[k0 + 3][dr] = u0.w;
        sm.p.Ts[k0 + 4][dr] = u1.x; sm.p.Ts[k0 + 5][dr] = u1.y;
        sm.p.Ts[k0 + 6][dr] = u1.z; sm.p.Ts[k0 + 7][dr] = u1.w;
        __syncthreads();
        int k = t >> 3, dc = (t & 7) * 8;
        union { unsigned short s[8]; uint4 v; } pk;
#pragma unroll
        for (int i = 0; i < 8; i++) pk.s[i] = f2b(sm.p.Ts[k][dc + i] * sc);
        *(uint4*)(Wt + (h * 32 + k) * D + d0 + dc) = pk.v;
    } else {
        Bq[t] = f2b(Qb[t] * 0.0625f); Bk[t] = f2b(Kb[t]); Bv[t] = f2b(Vb[t]);
    }
    __syncthreads();
}

__device__ __forceinline__ void proj_body(int bx, SMemU& sm,
    const float* __restrict__ x,
    const float* __restrict__ peQ, const float* __restrict__ peK,
    const unsigned short* __restrict__ WQt, const unsigned short* __restrict__ WKt,
    const unsigned short* __restrict__ WVt,
    const unsigned short* __restrict__ Bq, const unsigned short* __restrict__ Bk,
    const unsigned short* __restrict__ Bv,
    unsigned short* __restrict__ Qc, unsigned short* __restrict__ KV) {
    int which = bx >> 8, bb = bx & 255;
    const float* A1; const unsigned short* Bt; const unsigned short* bias; int K;
    if (which == 0)      { A1 = peQ; Bt = WQt; bias = Bq; K = 1024; }
    else if (which == 1) { A1 = peK; Bt = WKt; bias = Bk; K = 1024; }
    else                 { A1 = peQ; Bt = WVt; bias = Bv; K = 256; }
    int mb = bb & 63, nb = bb >> 6;
    int m0 = mb * 64, n0 = nb * 64;
    int t = threadIdx.x, w = t >> 6, lane = t & 63;
    int ln = lane & 15, q8 = (lane >> 4) * 8;
    int wm = (w >> 1) * 32, wn = (w & 1) * 32;
    int sr = t >> 3, sc = (t & 7) * 8;
    f32x4 acc[2][2];
#pragma unroll
    for (int i = 0; i < 2; i++)
#pragma unroll
        for (int j = 0; j < 2; j++) acc[i][j] = (f32x4){0.f, 0.f, 0.f, 0.f};
    for (int kb = 0; kb < K; kb += 64) {
#pragma unroll
        for (int half = 0; half < 2; half++) {
            int r = sr + half * 32;
            int c = kb + sc;
            const float* ap = (c < 256)
                ? (x + (m0 + r) * 256 + c)
                : (A1 + (m0 + r) * 768 + (c - 256));
            float4 u0 = *(const float4*)ap;
            float4 u1 = *(const float4*)(ap + 4);
            union { unsigned u[4]; uint4 v; } pk;
            pk.u[0] = pk2(u0.x, u0.y); pk.u[1] = pk2(u0.z, u0.w);
            pk.u[2] = pk2(u1.x, u1.y); pk.u[3] = pk2(u1.z, u1.w);
            *(uint4*)&sm.g.As[r * 72 + sc] = pk.v;
            *(uint4*)&sm.g.Bs[r * 72 + sc] = *(const uint4*)(Bt + (n0 + r) * K + c);
        }
        __syncthreads();
#pragma unroll
        for (int ks = 0; ks < 64; ks += 32) {
            bf16x8 a[2], b[2];
#pragma unroll
            for (int i = 0; i < 2; i++) {
                a[i] = *(const bf16x8*)&sm.g.As[(wm + i * 16 + ln) * 72 + ks + q8];
                b[i] = *(const bf16x8*)&sm.g.Bs[(wn + i * 16 + ln) * 72 + ks + q8];
            }
#pragma unroll
            for (int i = 0; i < 2; i++)
#pragma unroll
                for (int j = 0; j < 2; j++)
                    acc[i][j] = __builtin_amdgcn_mfma_f32_16x16x32_bf16(a[i], b[j], acc[i][j], 0, 0, 0);
        }
        __syncthreads();
    }
#pragma unroll
    for (int j = 0; j < 2; j++) {
        int ncol = n0 + wn + j * 16 + ln;
        float bv = b2f(bias[ncol]);
        int h2 = ncol >> 5, din = ncol & 31;
#pragma unroll
        for (int i = 0; i < 2; i++) {
            int rbase = m0 + wm + i * 16 + ((lane >> 4) * 4);
            if (which == 0) {
#pragma unroll
                for (int r = 0; r < 4; r++)
                    Qc[(rbase + r) * 256 + ncol] = f2b(acc[i][j][r] + bv);
            } else if (which == 1) {
#pragma unroll
                for (int r = 0; r < 4; r++) {
                    int key = rbase + r;
                    int T2 = key >> 6, k6 = key & 63;
                    int kt = ((k6 >> 2) & 1) + ((k6 >> 4) & 2);
                    int ln2 = ((k6 >> 3) & 3) * 4 + (k6 & 3);
                    int addr = (h2 * 64 + T2) * 4096 + kt * 512
                             + ((din >> 3) * 16 + ln2) * 8 + (din & 7);
                    KV[addr] = f2b(acc[i][j][r] + bv);
                }
            } else {
                int key = rbase;
                int T2 = key >> 6, k6 = key & 63;
                int chunk = 4 + ((din >> 4) << 1) + ((k6 >> 5) & 1);
                int lane2 = ((k6 >> 3) & 3) * 16 + (din & 15);
                int addr = (h2 * 64 + T2) * 4096 + chunk * 512 + lane2 * 8 + (k6 & 7);
                uint2 vv;
                vv.x = pk2(acc[i][j][0] + bv, acc[i][j][1] + bv);
                vv.y = pk2(acc[i][j][2] + bv, acc[i][j][3] + bv);
                *(uint2*)(KV + addr) = vv;
            }
        }
    }
    __syncthreads();
}

__device__ __forceinline__ void attn_body(int bid, SMemU& sm,
    const unsigned short* __restrict__ Qc,
    const unsigned short* __restrict__ KV,
    unsigned short* __restrict__ Xc) {
    int head = bid >> 7;
    int qb = bid & 127;
    int t = threadIdx.x, w = t >> 6, lane = t & 63;
    int ln = lane & 15, quad = lane >> 4, q8 = quad * 8;
    int q0 = qb * 32;
    bf16x8 qfv[2];
#pragma unroll
    for (int qf = 0; qf < 2; qf++)
        qfv[qf] = *(const bf16x8*)(Qc + (q0 + qf * 16 + ln) * 256 + head * 32 + q8);
    const unsigned short* kv = KV + (head * 64 + w * 16) * 4096 + lane * 8;
    f32x4 o[2][2];
#pragma unroll
    for (int qf = 0; qf < 2; qf++)
#pragma unroll
        for (int hh = 0; hh < 2; hh++) o[qf][hh] = (f32x4){0.f, 0.f, 0.f, 0.f};
    const f32x4 z = {0.f, 0.f, 0.f, 0.f};
    f32x4 lacc[2]; lacc[0] = z; lacc[1] = z;
    bf16x8 k0 = *(const bf16x8*)(kv + 0);
    bf16x8 k1 = *(const bf16x8*)(kv + 512);
    bf16x8 k2 = *(const bf16x8*)(kv + 1024);
    bf16x8 k3 = *(const bf16x8*)(kv + 1536);
    bf16x8 v0 = *(const bf16x8*)(kv + 2048);
    bf16x8 v1 = *(const bf16x8*)(kv + 2560);
    bf16x8 v2 = *(const bf16x8*)(kv + 3072);
    bf16x8 v3 = *(const bf16x8*)(kv + 3584);
#pragma unroll 1
    for (int it = 0; it < 16; it++) {
        int nit = (it < 15) ? (it + 1) : 15;
        const unsigned short* nkv = kv + nit * 4096;
        bf16x8 nk0 = *(const bf16x8*)(nkv + 0);
        bf16x8 nk1 = *(const bf16x8*)(nkv + 512);
        bf16x8 nk2 = *(const bf16x8*)(nkv + 1024);
        bf16x8 nk3 = *(const bf16x8*)(nkv + 1536);
        bf16x8 nv0 = *(const bf16x8*)(nkv + 2048);
        bf16x8 nv1 = *(const bf16x8*)(nkv + 2560);
        bf16x8 nv2 = *(const bf16x8*)(nkv + 3072);
        bf16x8 nv3 = *(const bf16x8*)(nkv + 3584);
#pragma unroll
        for (int qf = 0; qf < 2; qf++) {
            f32x4 s0 = __builtin_amdgcn_mfma_f32_16x16x32_bf16(k0, qfv[qf], z, 0, 0, 0);
            f32x4 s1 = __builtin_amdgcn_mfma_f32_16x16x32_bf16(k1, qfv[qf], z, 0, 0, 0);
            f32x4 s2 = __builtin_amdgcn_mfma_f32_16x16x32_bf16(k2, qfv[qf], z, 0, 0, 0);
            f32x4 s3 = __builtin_amdgcn_mfma_f32_16x16x32_bf16(k3, qfv[qf], z, 0, 0, 0);
            float p0[4], p1[4], p2[4], p3[4];
#pragma unroll
            for (int r = 0; r < 4; r++) {
                p0[r] = __expf(s0[r]); p1[r] = __expf(s1[r]);
                p2[r] = __expf(s2[r]); p3[r] = __expf(s3[r]);
            }
            f32x4 ps;
#pragma unroll
            for (int r = 0; r < 4; r++) ps[r] = (p0[r] + p1[r]) + (p2[r] + p3[r]);
            lacc[qf] += ps;
            union { unsigned u[4]; bf16x8 v; } b0, b1;
            b0.u[0] = pk2(p0[0], p0[1]); b0.u[1] = pk2(p0[2], p0[3]);
            b0.u[2] = pk2(p1[0], p1[1]); b0.u[3] = pk2(p1[2], p1[3]);
            b1.u[0] = pk2(p2[0], p2[1]); b1.u[1] = pk2(p2[2], p2[3]);
            b1.u[2] = pk2(p3[0], p3[1]); b1.u[3] = pk2(p3[2], p3[3]);
            o[qf][0] = __builtin_amdgcn_mfma_f32_16x16x32_bf16(v0, b0.v, o[qf][0], 0, 0, 0);
            o[qf][0] = __builtin_amdgcn_mfma_f32_16x16x32_bf16(v1, b1.v, o[qf][0], 0, 0, 0);
            o[qf][1] = __builtin_amdgcn_mfma_f32_16x16x32_bf16(v2, b0.v, o[qf][1], 0, 0, 0);
            o[qf][1] = __builtin_amdgcn_mfma_f32_16x16x32_bf16(v3, b1.v, o[qf][1], 0, 0, 0);
        }
        k0 = nk0; k1 = nk1; k2 = nk2; k3 = nk3;
        v0 = nv0; v1 = nv1; v2 = nv2; v3 = nv3;
    }
#pragma unroll
    for (int qf = 0; qf < 2; qf++) {
        float lts = (lacc[qf][0] + lacc[qf][1]) + (lacc[qf][2] + lacc[qf][3]);
        lts += __shfl_xor(lts, 16, 64);
        lts += __shfl_xor(lts, 32, 64);
#pragma unroll
        for (int r = 0; r < 4; r++) {
            sm.a.Om[w][quad * 4 + r][qf * 16 + ln] = o[qf][0][r];
            sm.a.Om[w][16 + quad * 4 + r][qf * 16 + ln] = o[qf][1][r];
        }
        if (quad == 0) sm.a.Ls[w][qf * 16 + ln] = lts;
    }
    __syncthreads();
    int q = t & 31, d = (t >> 5) * 4;
    float num[4] = {0.f, 0.f, 0.f, 0.f};
    float den = 0.f;
#pragma unroll
    for (int w2 = 0; w2 < 4; w2++) {
        den += sm.a.Ls[w2][q];
#pragma unroll
        for (int i = 0; i < 4; i++) num[i] += sm.a.Om[w2][d + i][q];
    }
    float inv = 1.f / den;
    uint2 outv;
    outv.x = pk2(num[0] * inv, num[1] * inv);
    outv.y = pk2(num[2] * inv, num[3] * inv);
    *(uint2*)(Xc + (q0 + q) * 256 + head * 32 + d) = outv;
    __syncthreads();
}

__device__ __forceinline__ void out_body(int bid, SMemU& sm,
    const unsigned short* __restrict__ A,
    const float* __restrict__ LW,
    const float* __restrict__ Lb,
    float* __restrict__ C) {
    int mb = bid & 63, nb = bid >> 6;
    int m0 = mb * 64, n0 = nb * 64;
    int t = threadIdx.x, w = t >> 6, lane = t & 63;
    int ln = lane & 15, q8 = (lane >> 4) * 8;
    int wm = (w >> 1) * 32, wn = (w & 1) * 32;
    int sr = t >> 3, sc = (t & 7) * 8;
    f32x4 acc[2][2];
#pragma unroll
    for (int i = 0; i < 2; i++)
#pragma unroll
        for (int j = 0; j < 2; j++) acc[i][j] = (f32x4){0.f, 0.f, 0.f, 0.f};
    for (int kb = 0; kb < 256; kb += 64) {
#pragma unroll
        for (int half = 0; half < 2; half++) {
            int r = sr + half * 32;
            int c = kb + sc;
            *(uint4*)&sm.g.As[r * 72 + sc] = *(const uint4*)(A + (m0 + r) * 256 + c);
            const float* bp = LW + (n0 + r) * 256 + c;
            float4 u0 = *(const float4*)bp;
            float4 u1 = *(const float4*)(bp + 4);
            union { unsigned u[4]; uint4 v; } pk;
            pk.u[0] = pk2(u0.x, u0.y); pk.u[1] = pk2(u0.z, u0.w);
            pk.u[2] = pk2(u1.x, u1.y); pk.u[3] = pk2(u1.z, u1.w);
            *(uint4*)&sm.g.Bs[r * 72 + sc] = pk.v;
        }
        __syncthreads();
#pragma unroll
        for (int ks = 0; ks < 64; ks += 32) {
            bf16x8 a[2], b[2];
#pragma unroll
            for (int i = 0; i < 2; i++) {
                a[i] = *(const bf16x8*)&sm.g.As[(wm + i * 16 + ln) * 72 + ks + q8];
                b[i] = *(const bf16x8*)&sm.g.Bs[(wn + i * 16 + ln) * 72 + ks + q8];
            }
#pragma unroll
            for (int i = 0; i < 2; i++)
#pragma unroll
                for (int j = 0; j < 2; j++)
                    acc[i][j] = __builtin_amdgcn_mfma_f32_16x16x32_bf16(a[i], b[j], acc[i][j], 0, 0, 0);
        }
        __syncthreads();
    }
#pragma unroll
    for (int j = 0; j < 2; j++) {
        int ncol = n0 + wn + j * 16 + ln;
        float bv = Lb[ncol];
#pragma unroll
        for (int i = 0; i < 2; i++) {
            int rbase = m0 + wm + i * 16 + ((lane >> 4) * 4);
#pragma unroll
            for (int r = 0; r < 4; r++)
                C[(rbase + r) * 256 + ncol] = acc[i][j][r] + bv;
        }
    }
    __syncthreads();
}

// ---------------- fused cooperative kernel ----------------
__global__ __launch_bounds__(256, 4) void mega(
    const float* x, const float* peQ, const float* peK,
    const float* WQ, const float* WK, const float* WV,
    const float* Qb, const float* Kb, const float* Vb,
    const float* LW, const float* Lb,
    unsigned short* WQt, unsigned short* WKt, unsigned short* WVt,
    unsigned short* Bq, unsigned short* Bk, unsigned short* Bv,
    unsigned short* Qc, unsigned short* KV, unsigned short* Xc,
    float* out) {
    __shared__ SMemU sm;
    cg::grid_group grid = cg::this_grid();
    int G = gridDim.x, bid = blockIdx.x;
    for (int vb = bid; vb < 289; vb += G)
        prep_body(vb, sm, WQ, WK, WV, Qb, Kb, Vb, WQt, WKt, WVt, Bq, Bk, Bv);
    grid.sync();
    for (int vb = bid; vb < 768; vb += G)
        proj_body(vb, sm, x, peQ, peK, WQt, WKt, WVt, Bq, Bk, Bv, Qc, KV);
    grid.sync();
    for (int vb = bid; vb < 1024; vb += G)
        attn_body(vb, sm, Qc, KV, Xc);
    grid.sync();
    for (int vb = bid; vb < 256; vb += G)
        out_body(vb, sm, Xc, LW, Lb, out);
}

// ---------------- standalone fallbacks (round-10 config) ----------------
__global__ __launch_bounds__(256) void k_prep(
    const float* WQ, const float* WK, const float* WV,
    const float* Qb, const float* Kb, const float* Vb,
    unsigned short* WQt, unsigned short* WKt, unsigned short* WVt,
    unsigned short* Bq, unsigned short* Bk, unsigned short* Bv) {
    __shared__ SMemU sm;
    prep_body(blockIdx.x, sm, WQ, WK, WV, Qb, Kb, Vb, WQt, WKt, WVt, Bq, Bk, Bv);
}
__global__ __launch_bounds__(256) void k_proj(
    const float* x, const float* peQ, const float* peK,
    const unsigned short* WQt, const unsigned short* WKt, const unsigned short* WVt,
    const unsigned short* Bq, const unsigned short* Bk, const unsigned short* Bv,
    unsigned short* Qc, unsigned short* KV) {
    __shared__ SMemU sm;
    proj_body(blockIdx.x, sm, x, peQ, peK, WQt, WKt, WVt, Bq, Bk, Bv, Qc, KV);
}
__global__ __launch_bounds__(256, 4) void k_attn(
    const unsigned short* Qc, const unsigned short* KV, unsigned short* Xc) {
    __shared__ SMemU sm;
    attn_body(blockIdx.x, sm, Qc, KV, Xc);
}
__global__ __launch_bounds__(256) void k_out(
    const unsigned short* A, const float* LW, const float* Lb, float* C) {
    __shared__ SMemU sm;
    out_body(blockIdx.x, sm, A, LW, Lb, C);
}

extern "C" void kernel_launch(void* const* d_in, const int* in_sizes, int n_in,
                              void* d_out, int out_size, void* d_ws, size_t ws_size,
                              hipStream_t stream) {
    const float* input_x = (const float*)d_in[0];
    const float* pe_Q    = (const float*)d_in[1];
    const float* pe_K    = (const float*)d_in[2];
    // d_in[3] = A (unused)
    const float* WQ = (const float*)d_in[4];
    const float* WK = (const float*)d_in[5];
    const float* WV = (const float*)d_in[6];
    const float* Qb = (const float*)d_in[7];
    const float* Kb = (const float*)d_in[8];
    const float* Vb = (const float*)d_in[9];
    const float* lw = (const float*)d_in[10];
    const float* lb = (const float*)d_in[11];

    unsigned short* ws = (unsigned short*)d_ws;
    unsigned short* WQt = ws;                  // 262144
    unsigned short* WKt = WQt + 262144;        // 262144
    unsigned short* WVt = WKt + 262144;        // 65536
    unsigned short* Bq  = WVt + 65536;         // 256 x3
    unsigned short* Bk  = Bq + 256;
    unsigned short* Bv  = Bk + 256;
    unsigned short* Qc  = Bv + 256;            // 4096*256
    unsigned short* KVb = Qc + 1048576;        // 8*64*4096 = 2097152
    unsigned short* Xc  = KVb + 2097152;       // 4096*256
    float* outp = (float*)d_out;

    int maxb = 0;
    hipError_t occ = hipOccupancyMaxActiveBlocksPerMultiprocessor(&maxb, mega, 256, 0);
    if (occ == hipSuccess && maxb >= 1) {
        int grid = maxb * 256; if (grid > 1024) grid = 1024;
        void* args[] = {
            (void*)&input_x, (void*)&pe_Q, (void*)&pe_K,
            (void*)&WQ, (void*)&WK, (void*)&WV,
            (void*)&Qb, (void*)&Kb, (void*)&Vb,
            (void*)&lw, (void*)&lb,
            (void*)&WQt, (void*)&WKt, (void*)&WVt,
            (void*)&Bq, (void*)&Bk, (void*)&Bv,
            (void*)&Qc, (void*)&KVb, (void*)&Xc,
            (void*)&outp };
        hipLaunchCooperativeKernel((const void*)mega, dim3(grid), dim3(256),
                                   args, 0, stream);
    } else {
        k_prep<<<dim3(289), dim3(256), 0, stream>>>(WQ, WK, WV, Qb, Kb, Vb,
                                                    WQt, WKt, WVt, Bq, Bk, Bv);
        k_proj<<<dim3(768), dim3(256), 0, stream>>>(input_x, pe_Q, pe_K,
                                                    WQt, WKt, WVt, Bq, Bk, Bv,
                                                    Qc, KVb);
        k_attn<<<dim3(1024), dim3(256), 0, stream>>>(Qc, KVb, Xc);
        k_out<<<dim3(256), dim3(256), 0, stream>>>(Xc, lw, lb, outp);
    }
}

// Round 13
// 180.665 us; speedup vs baseline: 2.0934x; 2.0934x over previous
//
#include <hip/hip_runtime.h>
#include <hip/hip_bf16.h>

typedef __attribute__((ext_vector_type(8))) short bf16x8;
typedef __attribute__((ext_vector_type(4))) float f32x4;

__device__ __forceinline__ unsigned short f2b(float f) {
    union { float f; unsigned int u; } v; v.f = f;
    unsigned int u = v.u;
    unsigned int r = (u + 0x7FFFu + ((u >> 16) & 1u)) >> 16;  // RNE
    return (unsigned short)r;
}
__device__ __forceinline__ float b2f(unsigned short h) {
    union { unsigned int u; float f; } v; v.u = ((unsigned int)h) << 16;
    return v.f;
}
__device__ __forceinline__ unsigned pk2(float a, float b) {
    union { __hip_bfloat162 h; unsigned u; } c;
    c.h = __float22bfloat162_rn(make_float2(a, b));
    return c.u;
}

// ---------- prep (bf16 path): weights + lin_w + biases + activations ----------
// b<288: W tiles; 288..319: lin_w; 320: biases; 321..3904: x/peQ/peK -> bf16.
__global__ __launch_bounds__(256) void prep_main(
    const float* __restrict__ WQ, const float* __restrict__ WK,
    const float* __restrict__ WV, const float* __restrict__ LW,
    const float* __restrict__ Qb, const float* __restrict__ Kb,
    const float* __restrict__ Vb,
    const float* __restrict__ x, const float* __restrict__ peQ,
    const float* __restrict__ peK,
    unsigned short* __restrict__ WQt, unsigned short* __restrict__ WKt,
    unsigned short* __restrict__ WVt, unsigned short* __restrict__ LWt,
    unsigned short* __restrict__ Bq, unsigned short* __restrict__ Bk,
    unsigned short* __restrict__ Bv,
    unsigned short* __restrict__ xb, unsigned short* __restrict__ peQb,
    unsigned short* __restrict__ peKb) {
    int b = blockIdx.x, t = threadIdx.x;
    if (b < 288) {
        const float* W; unsigned short* Wt; int h, d0, D; float sc = 1.0f;
        if (b < 128)      { W = WQ; Wt = WQt; h = b >> 4;   d0 = (b & 15) * 64; D = 1024; sc = 0.0625f; }
        else if (b < 256) { int bb = b - 128; W = WK; Wt = WKt; h = bb >> 4; d0 = (bb & 15) * 64; D = 1024; }
        else              { int bb = b - 256; W = WV; Wt = WVt; h = bb >> 2; d0 = (bb & 3) * 64;  D = 256; }
        __shared__ float Ts[32][65];
        int dr = t >> 2, k0 = (t & 3) * 8;
        const float* src = W + (h * D + d0 + dr) * 32 + k0;
        float4 u0 = *(const float4*)src;
        float4 u1 = *(const float4*)(src + 4);
        Ts[k0 + 0][dr] = u0.x; Ts[k0 + 1][dr] = u0.y; Ts[k0 + 2][dr] = u0.z; Ts[k0 + 3][dr] = u0.w;
        Ts[k0 + 4][dr] = u1.x; Ts[k0 + 5][dr] = u1.y; Ts[k0 + 6][dr] = u1.z; Ts[k0 + 7][dr] = u1.w;
        __syncthreads();
        int k = t >> 3, dc = (t & 7) * 8;
        union { unsigned short s[8]; uint4 v; } pk;
#pragma unroll
        for (int i = 0; i < 8; i++) pk.s[i] = f2b(Ts[k][dc + i] * sc);
        *(uint4*)(Wt + (h * 32 + k) * D + d0 + dc) = pk.v;
    } else if (b < 320) {
        int base = (b - 288) * 2048 + t * 8;
        const float* sp = LW + base;
        float4 u0 = *(const float4*)sp;
        float4 u1 = *(const float4*)(sp + 4);
        union { unsigned u[4]; uint4 v; } pk;
        pk.u[0] = pk2(u0.x, u0.y); pk.u[1] = pk2(u0.z, u0.w);
        pk.u[2] = pk2(u1.x, u1.y); pk.u[3] = pk2(u1.z, u1.w);
        *(uint4*)(LWt + base) = pk.v;
    } else if (b == 320) {
        Bq[t] = f2b(Qb[t] * 0.0625f); Bk[t] = f2b(Kb[t]); Bv[t] = f2b(Vb[t]);
    } else {
        int idx = (b - 321) * 2048 + t * 8;
        const float* sp; unsigned short* dp;
        if (idx < 1048576)      { sp = x + idx;                dp = xb + idx; }
        else if (idx < 4194304) { sp = peQ + (idx - 1048576);  dp = peQb + (idx - 1048576); }
        else                    { sp = peK + (idx - 4194304);  dp = peKb + (idx - 4194304); }
        float4 u0 = *(const float4*)sp;
        float4 u1 = *(const float4*)(sp + 4);
        union { unsigned u[4]; uint4 v; } pk;
        pk.u[0] = pk2(u0.x, u0.y); pk.u[1] = pk2(u0.z, u0.w);
        pk.u[2] = pk2(u1.x, u1.y); pk.u[3] = pk2(u1.z, u1.w);
        *(uint4*)dp = pk.v;
    }
}

// ---------- prep (fallback, round-10): weights + biases only ----------
__global__ __launch_bounds__(256) void prep_fb(
    const float* __restrict__ WQ, const float* __restrict__ WK,
    const float* __restrict__ WV,
    const float* __restrict__ Qb, const float* __restrict__ Kb,
    const float* __restrict__ Vb,
    unsigned short* __restrict__ WQt, unsigned short* __restrict__ WKt,
    unsigned short* __restrict__ WVt,
    unsigned short* __restrict__ Bq, unsigned short* __restrict__ Bk,
    unsigned short* __restrict__ Bv) {
    int b = blockIdx.x, t = threadIdx.x;
    if (b < 288) {
        const float* W; unsigned short* Wt; int h, d0, D; float sc = 1.0f;
        if (b < 128)      { W = WQ; Wt = WQt; h = b >> 4;   d0 = (b & 15) * 64; D = 1024; sc = 0.0625f; }
        else if (b < 256) { int bb = b - 128; W = WK; Wt = WKt; h = bb >> 4; d0 = (bb & 15) * 64; D = 1024; }
        else              { int bb = b - 256; W = WV; Wt = WVt; h = bb >> 2; d0 = (bb & 3) * 64;  D = 256; }
        __shared__ float Ts[32][65];
        int dr = t >> 2, k0 = (t & 3) * 8;
        const float* src = W + (h * D + d0 + dr) * 32 + k0;
        float4 u0 = *(const float4*)src;
        float4 u1 = *(const float4*)(src + 4);
        Ts[k0 + 0][dr] = u0.x; Ts[k0 + 1][dr] = u0.y; Ts[k0 + 2][dr] = u0.z; Ts[k0 + 3][dr] = u0.w;
        Ts[k0 + 4][dr] = u1.x; Ts[k0 + 5][dr] = u1.y; Ts[k0 + 6][dr] = u1.z; Ts[k0 + 7][dr] = u1.w;
        __syncthreads();
        int k = t >> 3, dc = (t & 7) * 8;
        union { unsigned short s[8]; uint4 v; } pk;
#pragma unroll
        for (int i = 0; i < 8; i++) pk.s[i] = f2b(Ts[k][dc + i] * sc);
        *(uint4*)(Wt + (h * 32 + k) * D + d0 + dc) = pk.v;
    } else {
        Bq[t] = f2b(Qb[t] * 0.0625f); Bk[t] = f2b(Kb[t]); Bv[t] = f2b(Vb[t]);
    }
}

// ---------- fused Q/K/V projections (768 blocks, 64x64 tiles, BK=64) ----------
// ABF16: activations already bf16 (xv/peQv/peKv are unsigned short*);
// else f32 with staging-convert. Q -> Qc row-major; K/V -> blocked KV.
template <bool ABF16>
__global__ __launch_bounds__(256) void proj_fused(
    const void* __restrict__ xv,
    const void* __restrict__ peQv, const void* __restrict__ peKv,
    const unsigned short* __restrict__ WQt, const unsigned short* __restrict__ WKt,
    const unsigned short* __restrict__ WVt,
    const unsigned short* __restrict__ Bq, const unsigned short* __restrict__ Bk,
    const unsigned short* __restrict__ Bv,
    unsigned short* __restrict__ Qc, unsigned short* __restrict__ KV) {
    __shared__ unsigned short As[64 * 72];
    __shared__ unsigned short Bs[64 * 72];
    int bx = blockIdx.x;
    int which = bx >> 8, bb = bx & 255;
    const void* A1; const unsigned short* Bt; const unsigned short* bias; int K;
    if (which == 0)      { A1 = peQv; Bt = WQt; bias = Bq; K = 1024; }
    else if (which == 1) { A1 = peKv; Bt = WKt; bias = Bk; K = 1024; }
    else                 { A1 = peQv; Bt = WVt; bias = Bv; K = 256; }
    int mb = bb & 63, nb = bb >> 6;
    int m0 = mb * 64, n0 = nb * 64;
    int t = threadIdx.x, w = t >> 6, lane = t & 63;
    int ln = lane & 15, q8 = (lane >> 4) * 8;
    int wm = (w >> 1) * 32, wn = (w & 1) * 32;
    int sr = t >> 3, sc = (t & 7) * 8;
    f32x4 acc[2][2];
#pragma unroll
    for (int i = 0; i < 2; i++)
#pragma unroll
        for (int j = 0; j < 2; j++) acc[i][j] = (f32x4){0.f, 0.f, 0.f, 0.f};
    for (int kb = 0; kb < K; kb += 64) {
#pragma unroll
        for (int half = 0; half < 2; half++) {
            int r = sr + half * 32;
            int c = kb + sc;
            if (ABF16) {
                const unsigned short* ap = (c < 256)
                    ? ((const unsigned short*)xv + (m0 + r) * 256 + c)
                    : ((const unsigned short*)A1 + (m0 + r) * 768 + (c - 256));
                *(uint4*)&As[r * 72 + sc] = *(const uint4*)ap;
            } else {
                const float* ap = (c < 256)
                    ? ((const float*)xv + (m0 + r) * 256 + c)
                    : ((const float*)A1 + (m0 + r) * 768 + (c - 256));
                float4 u0 = *(const float4*)ap;
                float4 u1 = *(const float4*)(ap + 4);
                union { unsigned u[4]; uint4 v; } pk;
                pk.u[0] = pk2(u0.x, u0.y); pk.u[1] = pk2(u0.z, u0.w);
                pk.u[2] = pk2(u1.x, u1.y); pk.u[3] = pk2(u1.z, u1.w);
                *(uint4*)&As[r * 72 + sc] = pk.v;
            }
            *(uint4*)&Bs[r * 72 + sc] = *(const uint4*)(Bt + (n0 + r) * K + c);
        }
        __syncthreads();
#pragma unroll
        for (int ks = 0; ks < 64; ks += 32) {
            bf16x8 a[2], b[2];
#pragma unroll
            for (int i = 0; i < 2; i++) {
                a[i] = *(const bf16x8*)&As[(wm + i * 16 + ln) * 72 + ks + q8];
                b[i] = *(const bf16x8*)&Bs[(wn + i * 16 + ln) * 72 + ks + q8];
            }
#pragma unroll
            for (int i = 0; i < 2; i++)
#pragma unroll
                for (int j = 0; j < 2; j++)
                    acc[i][j] = __builtin_amdgcn_mfma_f32_16x16x32_bf16(a[i], b[j], acc[i][j], 0, 0, 0);
        }
        __syncthreads();
    }
#pragma unroll
    for (int j = 0; j < 2; j++) {
        int ncol = n0 + wn + j * 16 + ln;
        float bv = b2f(bias[ncol]);
        int h2 = ncol >> 5, din = ncol & 31;
#pragma unroll
        for (int i = 0; i < 2; i++) {
            int rbase = m0 + wm + i * 16 + ((lane >> 4) * 4);
            if (which == 0) {
#pragma unroll
                for (int r = 0; r < 4; r++)
                    Qc[(rbase + r) * 256 + ncol] = f2b(acc[i][j][r] + bv);
            } else if (which == 1) {
#pragma unroll
                for (int r = 0; r < 4; r++) {
                    int key = rbase + r;
                    int T2 = key >> 6, k6 = key & 63;
                    int kt = ((k6 >> 2) & 1) + ((k6 >> 4) & 2);
                    int ln2 = ((k6 >> 3) & 3) * 4 + (k6 & 3);
                    int addr = (h2 * 64 + T2) * 4096 + kt * 512
                             + ((din >> 3) * 16 + ln2) * 8 + (din & 7);
                    KV[addr] = f2b(acc[i][j][r] + bv);
                }
            } else {
                int key = rbase;
                int T2 = key >> 6, k6 = key & 63;
                int chunk = 4 + ((din >> 4) << 1) + ((k6 >> 5) & 1);
                int lane2 = ((k6 >> 3) & 3) * 16 + (din & 15);
                int addr = (h2 * 64 + T2) * 4096 + chunk * 512 + lane2 * 8 + (k6 & 7);
                uint2 vv;
                vv.x = pk2(acc[i][j][0] + bv, acc[i][j][1] + bv);
                vv.y = pk2(acc[i][j][2] + bv, acc[i][j][3] + bv);
                *(uint2*)(KV + addr) = vv;
            }
        }
    }
}

// ---------- flash attention (round-10 proven: 41.4 us) ----------
__global__ __launch_bounds__(256, 4) void attn_kernel(
    const unsigned short* __restrict__ Qc,
    const unsigned short* __restrict__ KV,
    unsigned short* __restrict__ Xc) {
    __shared__ float Om[4][32][33];
    __shared__ float Ls[4][32];
    int head = blockIdx.x >> 7;
    int qb = blockIdx.x & 127;
    int t = threadIdx.x, w = t >> 6, lane = t & 63;
    int ln = lane & 15, quad = lane >> 4, q8 = quad * 8;
    int q0 = qb * 32;
    bf16x8 qfv[2];
#pragma unroll
    for (int qf = 0; qf < 2; qf++)
        qfv[qf] = *(const bf16x8*)(Qc + (q0 + qf * 16 + ln) * 256 + head * 32 + q8);
    const unsigned short* kv = KV + (head * 64 + w * 16) * 4096 + lane * 8;
    f32x4 o[2][2];
#pragma unroll
    for (int qf = 0; qf < 2; qf++)
#pragma unroll
        for (int hh = 0; hh < 2; hh++) o[qf][hh] = (f32x4){0.f, 0.f, 0.f, 0.f};
    const f32x4 z = {0.f, 0.f, 0.f, 0.f};
    f32x4 lacc[2]; lacc[0] = z; lacc[1] = z;
    bf16x8 k0 = *(const bf16x8*)(kv + 0);
    bf16x8 k1 = *(const bf16x8*)(kv + 512);
    bf16x8 k2 = *(const bf16x8*)(kv + 1024);
    bf16x8 k3 = *(const bf16x8*)(kv + 1536);
    bf16x8 v0 = *(const bf16x8*)(kv + 2048);
    bf16x8 v1 = *(const bf16x8*)(kv + 2560);
    bf16x8 v2 = *(const bf16x8*)(kv + 3072);
    bf16x8 v3 = *(const bf16x8*)(kv + 3584);
#pragma unroll 1
    for (int it = 0; it < 16; it++) {
        int nit = (it < 15) ? (it + 1) : 15;
        const unsigned short* nkv = kv + nit * 4096;
        bf16x8 nk0 = *(const bf16x8*)(nkv + 0);
        bf16x8 nk1 = *(const bf16x8*)(nkv + 512);
        bf16x8 nk2 = *(const bf16x8*)(nkv + 1024);
        bf16x8 nk3 = *(const bf16x8*)(nkv + 1536);
        bf16x8 nv0 = *(const bf16x8*)(nkv + 2048);
        bf16x8 nv1 = *(const bf16x8*)(nkv + 2560);
        bf16x8 nv2 = *(const bf16x8*)(nkv + 3072);
        bf16x8 nv3 = *(const bf16x8*)(nkv + 3584);
#pragma unroll
        for (int qf = 0; qf < 2; qf++) {
            f32x4 s0 = __builtin_amdgcn_mfma_f32_16x16x32_bf16(k0, qfv[qf], z, 0, 0, 0);
            f32x4 s1 = __builtin_amdgcn_mfma_f32_16x16x32_bf16(k1, qfv[qf], z, 0, 0, 0);
            f32x4 s2 = __builtin_amdgcn_mfma_f32_16x16x32_bf16(k2, qfv[qf], z, 0, 0, 0);
            f32x4 s3 = __builtin_amdgcn_mfma_f32_16x16x32_bf16(k3, qfv[qf], z, 0, 0, 0);
            float p0[4], p1[4], p2[4], p3[4];
#pragma unroll
            for (int r = 0; r < 4; r++) {
                p0[r] = __expf(s0[r]); p1[r] = __expf(s1[r]);
                p2[r] = __expf(s2[r]); p3[r] = __expf(s3[r]);
            }
            f32x4 ps;
#pragma unroll
            for (int r = 0; r < 4; r++) ps[r] = (p0[r] + p1[r]) + (p2[r] + p3[r]);
            lacc[qf] += ps;
            union { unsigned u[4]; bf16x8 v; } b0, b1;
            b0.u[0] = pk2(p0[0], p0[1]); b0.u[1] = pk2(p0[2], p0[3]);
            b0.u[2] = pk2(p1[0], p1[1]); b0.u[3] = pk2(p1[2], p1[3]);
            b1.u[0] = pk2(p2[0], p2[1]); b1.u[1] = pk2(p2[2], p2[3]);
            b1.u[2] = pk2(p3[0], p3[1]); b1.u[3] = pk2(p3[2], p3[3]);
            o[qf][0] = __builtin_amdgcn_mfma_f32_16x16x32_bf16(v0, b0.v, o[qf][0], 0, 0, 0);
            o[qf][0] = __builtin_amdgcn_mfma_f32_16x16x32_bf16(v1, b1.v, o[qf][0], 0, 0, 0);
            o[qf][1] = __builtin_amdgcn_mfma_f32_16x16x32_bf16(v2, b0.v, o[qf][1], 0, 0, 0);
            o[qf][1] = __builtin_amdgcn_mfma_f32_16x16x32_bf16(v3, b1.v, o[qf][1], 0, 0, 0);
        }
        k0 = nk0; k1 = nk1; k2 = nk2; k3 = nk3;
        v0 = nv0; v1 = nv1; v2 = nv2; v3 = nv3;
    }
#pragma unroll
    for (int qf = 0; qf < 2; qf++) {
        float lts = (lacc[qf][0] + lacc[qf][1]) + (lacc[qf][2] + lacc[qf][3]);
        lts += __shfl_xor(lts, 16, 64);
        lts += __shfl_xor(lts, 32, 64);
#pragma unroll
        for (int r = 0; r < 4; r++) {
            Om[w][quad * 4 + r][qf * 16 + ln] = o[qf][0][r];
            Om[w][16 + quad * 4 + r][qf * 16 + ln] = o[qf][1][r];
        }
        if (quad == 0) Ls[w][qf * 16 + ln] = lts;
    }
    __syncthreads();
    int q = t & 31, d = (t >> 5) * 4;
    float num[4] = {0.f, 0.f, 0.f, 0.f};
    float den = 0.f;
#pragma unroll
    for (int w2 = 0; w2 < 4; w2++) {
        den += Ls[w2][q];
#pragma unroll
        for (int i = 0; i < 4; i++) num[i] += Om[w2][d + i][q];
    }
    float inv = 1.f / den;
    uint2 outv;
    outv.x = pk2(num[0] * inv, num[1] * inv);
    outv.y = pk2(num[2] * inv, num[3] * inv);
    *(uint2*)(Xc + (q0 + q) * 256 + head * 32 + d) = outv;
}

// ---------- final GEMM: d_out f32 = Xc(bf16) @ lin_w^T + lin_b ----------
template <bool BBF16>
__global__ __launch_bounds__(256) void gemm_out(
    const unsigned short* __restrict__ A,
    const void* __restrict__ LWv,
    const float* __restrict__ Lb,
    float* __restrict__ C) {
    __shared__ unsigned short As[64 * 72];
    __shared__ unsigned short Bs[64 * 72];
    int mb = blockIdx.x & 63, nb = blockIdx.x >> 6;
    int m0 = mb * 64, n0 = nb * 64;
    int t = threadIdx.x, w = t >> 6, lane = t & 63;
    int ln = lane & 15, q8 = (lane >> 4) * 8;
    int wm = (w >> 1) * 32, wn = (w & 1) * 32;
    int sr = t >> 3, sc = (t & 7) * 8;
    f32x4 acc[2][2];
#pragma unroll
    for (int i = 0; i < 2; i++)
#pragma unroll
        for (int j = 0; j < 2; j++) acc[i][j] = (f32x4){0.f, 0.f, 0.f, 0.f};
    for (int kb = 0; kb < 256; kb += 64) {
#pragma unroll
        for (int half = 0; half < 2; half++) {
            int r = sr + half * 32;
            int c = kb + sc;
            *(uint4*)&As[r * 72 + sc] = *(const uint4*)(A + (m0 + r) * 256 + c);
            if (BBF16) {
                *(uint4*)&Bs[r * 72 + sc] =
                    *(const uint4*)((const unsigned short*)LWv + (n0 + r) * 256 + c);
            } else {
                const float* bp = (const float*)LWv + (n0 + r) * 256 + c;
                float4 u0 = *(const float4*)bp;
                float4 u1 = *(const float4*)(bp + 4);
                union { unsigned u[4]; uint4 v; } pk;
                pk.u[0] = pk2(u0.x, u0.y); pk.u[1] = pk2(u0.z, u0.w);
                pk.u[2] = pk2(u1.x, u1.y); pk.u[3] = pk2(u1.z, u1.w);
                *(uint4*)&Bs[r * 72 + sc] = pk.v;
            }
        }
        __syncthreads();
#pragma unroll
        for (int ks = 0; ks < 64; ks += 32) {
            bf16x8 a[2], b[2];
#pragma unroll
            for (int i = 0; i < 2; i++) {
                a[i] = *(const bf16x8*)&As[(wm + i * 16 + ln) * 72 + ks + q8];
                b[i] = *(const bf16x8*)&Bs[(wn + i * 16 + ln) * 72 + ks + q8];
            }
#pragma unroll
            for (int i = 0; i < 2; i++)
#pragma unroll
                for (int j = 0; j < 2; j++)
                    acc[i][j] = __builtin_amdgcn_mfma_f32_16x16x32_bf16(a[i], b[j], acc[i][j], 0, 0, 0);
        }
        __syncthreads();
    }
#pragma unroll
    for (int j = 0; j < 2; j++) {
        int ncol = n0 + wn + j * 16 + ln;
        float bv = Lb[ncol];
#pragma unroll
        for (int i = 0; i < 2; i++) {
            int rbase = m0 + wm + i * 16 + ((lane >> 4) * 4);
#pragma unroll
            for (int r = 0; r < 4; r++)
                C[(rbase + r) * 256 + ncol] = acc[i][j][r] + bv;
        }
    }
}

extern "C" void kernel_launch(void* const* d_in, const int* in_sizes, int n_in,
                              void* d_out, int out_size, void* d_ws, size_t ws_size,
                              hipStream_t stream) {
    const float* input_x = (const float*)d_in[0];
    const float* pe_Q    = (const float*)d_in[1];
    const float* pe_K    = (const float*)d_in[2];
    // d_in[3] = A (unused)
    const float* WQ = (const float*)d_in[4];
    const float* WK = (const float*)d_in[5];
    const float* WV = (const float*)d_in[6];
    const float* Qb = (const float*)d_in[7];
    const float* Kb = (const float*)d_in[8];
    const float* Vb = (const float*)d_in[9];
    const float* lw = (const float*)d_in[10];
    const float* lb = (const float*)d_in[11];
    float* outp = (float*)d_out;

    unsigned short* ws = (unsigned short*)d_ws;
    unsigned short* WQt = ws;                  // 262144
    unsigned short* WKt = WQt + 262144;        // 262144
    unsigned short* WVt = WKt + 262144;        // 65536
    unsigned short* LWt = WVt + 65536;         // 65536
    unsigned short* Bq  = LWt + 65536;         // 256 x3
    unsigned short* Bk  = Bq + 256;
    unsigned short* Bv  = Bk + 256;
    unsigned short* xb   = Bv + 256;           // 1048576
    unsigned short* peQb = xb + 1048576;       // 3145728
    unsigned short* peKb = peQb + 3145728;     // 3145728
    unsigned short* Qc   = peKb + 3145728;     // 1048576
    unsigned short* KVb  = Qc + 1048576;       // 2097152
    unsigned short* Xc   = KVb + 2097152;      // 1048576
    size_t need = (size_t)(Xc + 1048576 - ws) * 2;

    if (ws_size >= need) {
        prep_main<<<dim3(3905), dim3(256), 0, stream>>>(
            WQ, WK, WV, lw, Qb, Kb, Vb, input_x, pe_Q, pe_K,
            WQt, WKt, WVt, LWt, Bq, Bk, Bv, xb, peQb, peKb);
        proj_fused<true><<<dim3(768), dim3(256), 0, stream>>>(
            xb, peQb, peKb, WQt, WKt, WVt, Bq, Bk, Bv, Qc, KVb);
        attn_kernel<<<dim3(1024), dim3(256), 0, stream>>>(Qc, KVb, Xc);
        gemm_out<true><<<dim3(256), dim3(256), 0, stream>>>(Xc, LWt, lb, outp);
    } else {
        // round-10 fallback (f32 staging), smaller footprint
        unsigned short* Qc2  = Bv + 256;
        unsigned short* KV2  = Qc2 + 1048576;
        unsigned short* Xc2  = KV2 + 2097152;
        prep_fb<<<dim3(289), dim3(256), 0, stream>>>(WQ, WK, WV, Qb, Kb, Vb,
                                                     WQt, WKt, WVt, Bq, Bk, Bv);
        proj_fused<false><<<dim3(768), dim3(256), 0, stream>>>(
            input_x, pe_Q, pe_K, WQt, WKt, WVt, Bq, Bk, Bv, Qc2, KV2);
        attn_kernel<<<dim3(1024), dim3(256), 0, stream>>>(Qc2, KV2, Xc2);
        gemm_out<false><<<dim3(256), dim3(256), 0, stream>>>(Xc2, lw, lb, outp);
    }
}